// Round 12
// baseline (61.810 us; speedup 1.0000x reference)
//
#include <hip/hip_runtime.h>
#include <hip/hip_bf16.h>

#define NPTS 2048      // N == M == 2048
#define QMIX 8
#define LATD 64
#define NIT  4         // i-tiles (16 rows each) per pair block

typedef float f32x4 __attribute__((ext_vector_type(4)));
typedef short short8 __attribute__((ext_vector_type(8)));   // 8 bf16 (4 VGPRs)

__device__ __forceinline__ float softplus_f(float x) {
    return fmaxf(x, 0.0f) + log1pf(expf(-fabsf(x)));
}
__device__ __forceinline__ float selu_f(float z) {
    const float sc = 1.0507009873554805f;
    const float sa = 1.7580993408473766f;
    return (z > 0.0f) ? sc * z : sa * expm1f(z);
}
__device__ __forceinline__ ushort bfrn(float v) {   // round-to-nearest bf16
    unsigned b = __float_as_uint(v);
    return (ushort)((b + 0x7fffu + ((b >> 16) & 1u)) >> 16);
}
__device__ __forceinline__ void split_bf16(float v, ushort& h, ushort& l) {
    unsigned b  = __float_as_uint(v);
    unsigned hb = b & 0xffff0000u;          // truncated hi
    h = (ushort)(hb >> 16);
    l = bfrn(v - __uint_as_float(hb));      // rounded residual
}
__device__ __forceinline__ short8 ct_frag(uint av) {
    // nonzero bf16 pair at elements 4,5 (k-slots 20,21 for the kb==2 group)
    int4 r; r.x = 0; r.y = 0; r.z = (int)av; r.w = 0;
    return __builtin_bit_cast(short8, r);
}

// Slot layout per (point, q), 32 bf16 slots (hi + lo arrays):
//  X rows: [0..9]=coef, [10..19]=monomials, [20..31]=0
//  Y rows: [0..9]=monomials, [10..19]=coef, [20..31]=0
//  coef      = EF*[A00,A11,A22,2A01,2A02,2A12, -2Ax0,-2Ax1,-2Ax2, pAp]
//  monomials = [p0^2,p1^2,p2^2,p0p1,p0p2,p1p2, p0,p1,p2, 1]
//  => dot(Xrow[i,q], Yrow[j,q]) = EF*(qx+qy) = u;  exp(-sqrt5*r)=exp2(-u)
//  CTX/CTY[pt*8+q] = packed bf16 {w*cos, w*sin}  (K=2 cosine dot, slots 20/21)
__global__ __launch_bounds__(640) void feat_kernel(
    const float* __restrict__ xin, const float* __restrict__ yin,
    const float* __restrict__ W1, const float* __restrict__ b1,
    const float* __restrict__ Ww, const float* __restrict__ bw,
    const float* __restrict__ Wf, const float* __restrict__ bf,
    const float* __restrict__ Ws, const float* __restrict__ bs,
    ushort* __restrict__ AXH, ushort* __restrict__ AXL,
    ushort* __restrict__ BYH, ushort* __restrict__ BYL,
    uint* __restrict__ CTX, uint* __restrict__ CTY)
{
    __shared__ float hsh[8][LATD + 4];
    __shared__ float raw[8][80];
    const int t = threadIdx.x;

    // phase 1: hidden layer
    if (t < 512) {
        const int pl = t & 7, l = t >> 3;
        const int g = blockIdx.x * 8 + pl;
        const bool isx = (g < NPTS);
        const float* pts = isx ? (xin + 3 * g) : (yin + 3 * (g - NPTS));
        const float z = fmaf(W1[l * 3 + 0], pts[0],
                        fmaf(W1[l * 3 + 1], pts[1],
                        fmaf(W1[l * 3 + 2], pts[2], b1[l])));
        hsh[pl][l] = selu_f(z);
    }
    __syncthreads();

    // phase 2: head dots
    {
        const int o  = t >> 3;
        const int pl = t & 7;
        const int q  = o / 10;
        const int e  = o % 10;
        const float* row;
        float acc;
        if (e == 0)      { row = Ww + q * LATD;                 acc = bw[q]; }
        else if (e <= 3) { row = Wf + (q * 3 + (e - 1)) * LATD; acc = bf[q * 3 + (e - 1)]; }
        else             { row = Ws + (q * 6 + (e - 4)) * LATD; acc = bs[q * 6 + (e - 4)]; }
#pragma unroll
        for (int l4 = 0; l4 < LATD / 4; ++l4) {
            const float4 rv = reinterpret_cast<const float4*>(row)[l4];
            const float4 hv = *reinterpret_cast<const float4*>(&hsh[pl][l4 * 4]);
            acc = fmaf(rv.x, hv.x, acc);
            acc = fmaf(rv.y, hv.y, acc);
            acc = fmaf(rv.z, hv.z, acc);
            acc = fmaf(rv.w, hv.w, acc);
        }
        raw[pl][o] = softplus_f(acc);
    }
    __syncthreads();

    // phase 3: expand quadratic form and emit split-bf16 rows
    if (t < 64) {
        const int pl2 = t >> 3, q2 = t & 7;
        const int g2  = blockIdx.x * 8 + pl2;
        const bool isx2 = (g2 < NPTS);
        const float* pts2 = isx2 ? (xin + 3 * g2) : (yin + 3 * (g2 - NPTS));
        const float c0 = pts2[0], c1 = pts2[1], c2 = pts2[2];
        const float* rr = raw[pl2] + q2 * 10;
        const float w  = rr[0];
        const float f0 = rr[1], f1 = rr[2], f2 = rr[3];
        const float s0 = rr[4], s1 = rr[5], s2 = rr[6];
        const float s3 = rr[7], s4 = rr[8], s5 = rr[9];

        // A = L L^T
        const float A00 = s0 * s0;
        const float A01 = s0 * s1;
        const float A02 = s0 * s3;
        const float A11 = fmaf(s1, s1, s2 * s2);
        const float A12 = fmaf(s1, s3, s2 * s4);
        const float A22 = fmaf(s3, s3, fmaf(s4, s4, s5 * s5));
        const float Ax0 = fmaf(A00, c0, fmaf(A01, c1, A02 * c2));
        const float Ax1 = fmaf(A01, c0, fmaf(A11, c1, A12 * c2));
        const float Ax2 = fmaf(A02, c0, fmaf(A12, c1, A22 * c2));
        const float pAp = fmaf(c0, Ax0, fmaf(c1, Ax1, c2 * Ax2));
        const float ph  = fmaf(f0, c0, fmaf(f1, c1, f2 * c2));
        float sn, cs;
        sincosf(6.283185307179586477f * ph, &sn, &cs);

        const float EF = 3.2259751249059600974f;   // sqrt(5)*log2(e)
        const float cf[10] = { EF * A00, EF * A11, EF * A22,
                               2.0f * EF * A01, 2.0f * EF * A02, 2.0f * EF * A12,
                               -2.0f * EF * Ax0, -2.0f * EF * Ax1, -2.0f * EF * Ax2,
                               EF * pAp };
        const float pv[10] = { c0 * c0, c1 * c1, c2 * c2,
                               c0 * c1, c0 * c2, c1 * c2,
                               c0, c1, c2, 1.0f };
        float slots[20];
#pragma unroll
        for (int k = 0; k < 10; ++k) {
            slots[k]      = isx2 ? cf[k] : pv[k];
            slots[10 + k] = isx2 ? pv[k] : cf[k];
        }
        ushort H[32], L[32];
#pragma unroll
        for (int k = 0; k < 32; ++k) { H[k] = 0; L[k] = 0; }
#pragma unroll
        for (int k = 0; k < 20; ++k) split_bf16(slots[k], H[k], L[k]);

        const int pi = isx2 ? g2 : (g2 - NPTS);
        ushort* dh = (isx2 ? AXH : BYH) + ((size_t)pi * 8 + q2) * 32;
        ushort* dl = (isx2 ? AXL : BYL) + ((size_t)pi * 8 + q2) * 32;
#pragma unroll
        for (int m = 0; m < 16; ++m) {
            ((uint*)dh)[m] = (uint)H[2 * m] | ((uint)H[2 * m + 1] << 16);
            ((uint*)dl)[m] = (uint)L[2 * m] | ((uint)L[2 * m + 1] << 16);
        }
        uint* ct = isx2 ? CTX : CTY;
        ct[(size_t)pi * 8 + q2] = (uint)bfrn(w * cs) | ((uint)bfrn(w * sn) << 16);
    }
}

// Pair kernel, pipelined: wave = one 16x16 output tile (j fixed, i looped).
// Double-buffered A-tile LDS staging with register prefetch: tile t+1's
// global loads issue BEFORE computing tile t (latency hidden under MFMA),
// LDS writes land after, ONE barrier per tile. Output goes through LDS for
// full-line coalesced stores (fixes r11's 44MB partial-line write traffic).
__global__ __launch_bounds__(256, 3) void pair_kernel(
    const ushort* __restrict__ AXH, const ushort* __restrict__ AXL,
    const uint*  __restrict__ CTX,
    const ushort* __restrict__ BYH, const ushort* __restrict__ BYL,
    const uint*  __restrict__ CTY, float* __restrict__ out)
{
    __shared__ ushort sAH[2][16 * 256];   // 2 x 8 KB (swizzled)
    __shared__ ushort sAL[2][16 * 256];   // 2 x 8 KB (swizzled)
    __shared__ uint   sCT[2][16 * 9];     // stride-9 padded
    __shared__ float  sOut[2][16][68];    // 2 x 4.25 KB (row 272B, 16B-aligned)
    const int t   = threadIdx.x;
    const int wv  = t >> 6, ln = t & 63;
    const int col = ln & 15, kb = ln >> 4;
    const int j0  = blockIdx.x * 64 + wv * 16;
    const int it0 = blockIdx.y * NIT;

    // resident B-side fragments (j-tile fixed for the whole block)
    short8 Bh[8], Bl[8];
    uint   cvY[8];
    {
        const ushort* bh = BYH + (size_t)(j0 + col) * 256 + kb * 8;
        const ushort* bl = BYL + (size_t)(j0 + col) * 256 + kb * 8;
#pragma unroll
        for (int q = 0; q < 8; ++q) {
            Bh[q] = *reinterpret_cast<const short8*>(bh + q * 32);
            Bl[q] = *reinterpret_cast<const short8*>(bl + q * 32);
            cvY[q] = (kb == 2) ? CTY[(size_t)(j0 + col) * 8 + q] : 0u;
        }
    }
    const float P1 = 0.69314718055994530942f;   // ln2
    const float P2 = 0.16013630893549922444f;   // ln2^2/3

    uint4 pH[2], pL[2];
    uint  pC;
    // stage_load: issue global loads for tile at row i0 into registers
#define STAGE_LOAD(I0)                                                        \
    {                                                                         \
        const uint4* srcH = reinterpret_cast<const uint4*>(AXH + (size_t)(I0) * 256); \
        const uint4* srcL = reinterpret_cast<const uint4*>(AXL + (size_t)(I0) * 256); \
        pH[0] = srcH[t]; pH[1] = srcH[t + 256];                               \
        pL[0] = srcL[t]; pL[1] = srcL[t + 256];                               \
        pC = (t < 128) ? CTX[(size_t)((I0) + (t >> 3)) * 8 + (t & 7)] : 0u;   \
    }
    // lds_write: commit staged registers to LDS buffer B (XOR-swizzled)
#define LDS_WRITE(B)                                                          \
    {                                                                         \
        _Pragma("unroll")                                                     \
        for (int u = 0; u < 2; ++u) {                                         \
            const int s   = t + u * 256;                                      \
            const int row = s >> 5, sl = s & 31;                              \
            const int ds  = row * 32 + (sl ^ row);                            \
            reinterpret_cast<uint4*>(sAH[B])[ds] = pH[u];                     \
            reinterpret_cast<uint4*>(sAL[B])[ds] = pL[u];                     \
        }                                                                     \
        if (t < 128) sCT[B][(t >> 3) * 9 + (t & 7)] = pC;                     \
    }

    STAGE_LOAD(it0 * 16)
    LDS_WRITE(0)
    __syncthreads();

    for (int it = 0; it < NIT; ++it) {
        const int i0  = (it0 + it) * 16;
        const int cur = it & 1;
        if (it + 1 < NIT) STAGE_LOAD((it0 + it + 1) * 16)   // prefetch t+1

        f32x4 kacc = {0.f, 0.f, 0.f, 0.f};
#pragma unroll
        for (int q = 0; q < 8; ++q) {
            // swizzled read: logical 16B-chunk (q*4+kb) of row col
            const int ro = col * 256 + (((q * 4 + kb) ^ col) << 3);
            const short8 Ah = *reinterpret_cast<const short8*>(sAH[cur] + ro);
            const short8 Al = *reinterpret_cast<const short8*>(sAL[cur] + ro);
            const f32x4 z = {0.f, 0.f, 0.f, 0.f};
            f32x4 au = __builtin_amdgcn_mfma_f32_16x16x32_bf16(Ah, Bh[q], z, 0, 0, 0);
            au = __builtin_amdgcn_mfma_f32_16x16x32_bf16(Al, Bh[q], au, 0, 0, 0);
            au = __builtin_amdgcn_mfma_f32_16x16x32_bf16(Ah, Bl[q], au, 0, 0, 0);
            const uint av = (kb == 2) ? sCT[cur][col * 9 + q] : 0u;
            const f32x4 ac = __builtin_amdgcn_mfma_f32_16x16x32_bf16(
                ct_frag(av), ct_frag(cvY[q]), z, 0, 0, 0);
#pragma unroll
            for (int e = 0; e < 4; ++e) {
                const float u  = au[e];
                const float po = fmaf(u, fmaf(u, P2, P1), 1.0f);
                const float ex = __builtin_amdgcn_exp2f(-u);
                kacc[e] = fmaf(po * ex, ac[e], kacc[e]);
            }
        }

        // D layout: row = kb*4+e, col = lane&15 -> stage tile in LDS
#pragma unroll
        for (int e = 0; e < 4; ++e)
            sOut[cur][kb * 4 + e][wv * 16 + col] = kacc[e];

        if (it + 1 < NIT) LDS_WRITE((it + 1) & 1)   // commit prefetched tile
        __syncthreads();

        // coalesced full-line store: one float4 per thread, 256B per row
        {
            const int r = t >> 4, c4 = (t & 15) * 4;
            const float4 v = *reinterpret_cast<const float4*>(&sOut[cur][r][c4]);
            *reinterpret_cast<float4*>(
                out + (size_t)(i0 + r) * NPTS + blockIdx.x * 64 + c4) = v;
        }
    }
#undef STAGE_LOAD
#undef LDS_WRITE
}

extern "C" void kernel_launch(void* const* d_in, const int* in_sizes, int n_in,
                              void* d_out, int out_size, void* d_ws, size_t ws_size,
                              hipStream_t stream) {
    const float* x  = (const float*)d_in[0];
    const float* y  = (const float*)d_in[1];
    const float* W1 = (const float*)d_in[2];
    const float* b1 = (const float*)d_in[3];
    const float* Ww = (const float*)d_in[4];
    const float* bw = (const float*)d_in[5];
    const float* Wf = (const float*)d_in[6];
    const float* bf = (const float*)d_in[7];
    const float* Ws = (const float*)d_in[8];
    const float* bs = (const float*)d_in[9];
    float* out = (float*)d_out;

    ushort* AXH = (ushort*)d_ws;                 // [2048][8][32] bf16 hi
    ushort* AXL = AXH + (size_t)NPTS * 256;      // lo
    ushort* BYH = AXL + (size_t)NPTS * 256;
    ushort* BYL = BYH + (size_t)NPTS * 256;
    uint*   CTX = (uint*)(BYL + (size_t)NPTS * 256);  // [2048][8] packed {wc,ws}
    uint*   CTY = CTX + (size_t)NPTS * 8;

    feat_kernel<<<dim3((2 * NPTS) / 8), dim3(640), 0, stream>>>(
        x, y, W1, b1, Ww, bw, Wf, bf, Ws, bs, AXH, AXL, BYH, BYL, CTX, CTY);

    // (32 j-blocks of 64 cols, 32 i-strips of NIT*16 rows)
    pair_kernel<<<dim3(NPTS / 64, NPTS / (NIT * 16)), dim3(256), 0, stream>>>(
        AXH, AXL, CTX, BYH, BYL, CTY, out);
}

// Round 13
// 49.186 us; speedup vs baseline: 1.2566x; 1.2566x over previous
//
#include <hip/hip_runtime.h>
#include <hip/hip_bf16.h>

#define NPTS 2048      // N == M == 2048
#define QMIX 8
#define LATD 64
#define NIT  2         // i-tiles (16 rows each) per pair block

typedef float f32x4 __attribute__((ext_vector_type(4)));
typedef short short8 __attribute__((ext_vector_type(8)));   // 8 bf16 (4 VGPRs)

__device__ __forceinline__ float softplus_f(float x) {
    return fmaxf(x, 0.0f) + log1pf(expf(-fabsf(x)));
}
__device__ __forceinline__ float selu_f(float z) {
    const float sc = 1.0507009873554805f;
    const float sa = 1.7580993408473766f;
    return (z > 0.0f) ? sc * z : sa * expm1f(z);
}
__device__ __forceinline__ ushort bfrn(float v) {   // round-to-nearest bf16
    unsigned b = __float_as_uint(v);
    return (ushort)((b + 0x7fffu + ((b >> 16) & 1u)) >> 16);
}
__device__ __forceinline__ void split_bf16(float v, ushort& h, ushort& l) {
    unsigned b  = __float_as_uint(v);
    unsigned hb = b & 0xffff0000u;          // truncated hi
    h = (ushort)(hb >> 16);
    l = bfrn(v - __uint_as_float(hb));      // rounded residual
}
__device__ __forceinline__ short8 ct_frag(uint av) {
    // nonzero bf16 pair at elements 4,5 (k-slots 20,21 for the kb==2 group)
    int4 r; r.x = 0; r.y = 0; r.z = (int)av; r.w = 0;
    return __builtin_bit_cast(short8, r);
}

// Slot layout per (point, q), 32 bf16 slots (hi + lo arrays):
//  X rows: [0..9]=coef, [10..19]=monomials, [20..31]=0
//  Y rows: [0..9]=monomials, [10..19]=coef, [20..31]=0
//  coef      = EF*[A00,A11,A22,2A01,2A02,2A12, -2Ax0,-2Ax1,-2Ax2, pAp]
//  monomials = [p0^2,p1^2,p2^2,p0p1,p0p2,p1p2, p0,p1,p2, 1]
//  => dot(Xrow[i,q], Yrow[j,q]) = EF*(qx+qy) = u;  exp(-sqrt5*r)=exp2(-u)
//
// FRAGMENT-READY TILED STORAGE (new in r13): element (pt, q, k-chunk kb)
// lives at  ushort_ofs = ((pt>>4)*8 + q)*512 + (pt&15)*32 + kb*8
// so a wave (lane = (col, kb)) loading tile/q reads ONE contiguous 1KB block.
// CTX/CTY[pt*8+q] = packed bf16 {w*cos, w*sin}  (K=2 cosine dot, slots 20/21)
__global__ __launch_bounds__(640) void feat_kernel(
    const float* __restrict__ xin, const float* __restrict__ yin,
    const float* __restrict__ W1, const float* __restrict__ b1,
    const float* __restrict__ Ww, const float* __restrict__ bw,
    const float* __restrict__ Wf, const float* __restrict__ bf,
    const float* __restrict__ Ws, const float* __restrict__ bs,
    ushort* __restrict__ AXH, ushort* __restrict__ AXL,
    ushort* __restrict__ BYH, ushort* __restrict__ BYL,
    uint* __restrict__ CTX, uint* __restrict__ CTY)
{
    __shared__ float hsh[8][LATD + 4];
    __shared__ float raw[8][80];
    const int t = threadIdx.x;

    // phase 1: hidden layer
    if (t < 512) {
        const int pl = t & 7, l = t >> 3;
        const int g = blockIdx.x * 8 + pl;
        const bool isx = (g < NPTS);
        const float* pts = isx ? (xin + 3 * g) : (yin + 3 * (g - NPTS));
        const float z = fmaf(W1[l * 3 + 0], pts[0],
                        fmaf(W1[l * 3 + 1], pts[1],
                        fmaf(W1[l * 3 + 2], pts[2], b1[l])));
        hsh[pl][l] = selu_f(z);
    }
    __syncthreads();

    // phase 2: head dots
    {
        const int o  = t >> 3;
        const int pl = t & 7;
        const int q  = o / 10;
        const int e  = o % 10;
        const float* row;
        float acc;
        if (e == 0)      { row = Ww + q * LATD;                 acc = bw[q]; }
        else if (e <= 3) { row = Wf + (q * 3 + (e - 1)) * LATD; acc = bf[q * 3 + (e - 1)]; }
        else             { row = Ws + (q * 6 + (e - 4)) * LATD; acc = bs[q * 6 + (e - 4)]; }
#pragma unroll
        for (int l4 = 0; l4 < LATD / 4; ++l4) {
            const float4 rv = reinterpret_cast<const float4*>(row)[l4];
            const float4 hv = *reinterpret_cast<const float4*>(&hsh[pl][l4 * 4]);
            acc = fmaf(rv.x, hv.x, acc);
            acc = fmaf(rv.y, hv.y, acc);
            acc = fmaf(rv.z, hv.z, acc);
            acc = fmaf(rv.w, hv.w, acc);
        }
        raw[pl][o] = softplus_f(acc);
    }
    __syncthreads();

    // phase 3: expand quadratic form and emit split-bf16 rows (tiled layout)
    if (t < 64) {
        const int pl2 = t >> 3, q2 = t & 7;
        const int g2  = blockIdx.x * 8 + pl2;
        const bool isx2 = (g2 < NPTS);
        const float* pts2 = isx2 ? (xin + 3 * g2) : (yin + 3 * (g2 - NPTS));
        const float c0 = pts2[0], c1 = pts2[1], c2 = pts2[2];
        const float* rr = raw[pl2] + q2 * 10;
        const float w  = rr[0];
        const float f0 = rr[1], f1 = rr[2], f2 = rr[3];
        const float s0 = rr[4], s1 = rr[5], s2 = rr[6];
        const float s3 = rr[7], s4 = rr[8], s5 = rr[9];

        // A = L L^T
        const float A00 = s0 * s0;
        const float A01 = s0 * s1;
        const float A02 = s0 * s3;
        const float A11 = fmaf(s1, s1, s2 * s2);
        const float A12 = fmaf(s1, s3, s2 * s4);
        const float A22 = fmaf(s3, s3, fmaf(s4, s4, s5 * s5));
        const float Ax0 = fmaf(A00, c0, fmaf(A01, c1, A02 * c2));
        const float Ax1 = fmaf(A01, c0, fmaf(A11, c1, A12 * c2));
        const float Ax2 = fmaf(A02, c0, fmaf(A12, c1, A22 * c2));
        const float pAp = fmaf(c0, Ax0, fmaf(c1, Ax1, c2 * Ax2));
        const float ph  = fmaf(f0, c0, fmaf(f1, c1, f2 * c2));
        float sn, cs;
        sincosf(6.283185307179586477f * ph, &sn, &cs);

        const float EF = 3.2259751249059600974f;   // sqrt(5)*log2(e)
        const float cf[10] = { EF * A00, EF * A11, EF * A22,
                               2.0f * EF * A01, 2.0f * EF * A02, 2.0f * EF * A12,
                               -2.0f * EF * Ax0, -2.0f * EF * Ax1, -2.0f * EF * Ax2,
                               EF * pAp };
        const float pv[10] = { c0 * c0, c1 * c1, c2 * c2,
                               c0 * c1, c0 * c2, c1 * c2,
                               c0, c1, c2, 1.0f };
        float slots[20];
#pragma unroll
        for (int k = 0; k < 10; ++k) {
            slots[k]      = isx2 ? cf[k] : pv[k];
            slots[10 + k] = isx2 ? pv[k] : cf[k];
        }
        ushort H[32], L[32];
#pragma unroll
        for (int k = 0; k < 32; ++k) { H[k] = 0; L[k] = 0; }
#pragma unroll
        for (int k = 0; k < 20; ++k) split_bf16(slots[k], H[k], L[k]);

        const int pi = isx2 ? g2 : (g2 - NPTS);
        const size_t ofs = (((size_t)(pi >> 4) * 8 + q2) * 512) + (size_t)(pi & 15) * 32;
        ushort* dh = (isx2 ? AXH : BYH) + ofs;
        ushort* dl = (isx2 ? AXL : BYL) + ofs;
#pragma unroll
        for (int m = 0; m < 16; ++m) {
            ((uint*)dh)[m] = (uint)H[2 * m] | ((uint)H[2 * m + 1] << 16);
            ((uint*)dl)[m] = (uint)L[2 * m] | ((uint)L[2 * m + 1] << 16);
        }
        uint* ct = isx2 ? CTX : CTY;
        ct[(size_t)pi * 8 + q2] = (uint)bfrn(w * cs) | ((uint)bfrn(w * sn) << 16);
    }
}

// Pair kernel r13: NO LDS, NO barriers. Wave = one 16x16 output tile
// (j fixed per wave, NIT i-tiles looped). A and B fragments both load
// directly from global in fragment-ready layout (1KB contiguous per wave
// instruction, L2-resident). Output via non-temporal stores so the
// 17MB write stream doesn't evict the 4MB A/B set from L2 (r11/r12's
// root stall). 2048 independent blocks, 16 waves/CU resident.
__global__ __launch_bounds__(256, 4) void pair_kernel(
    const ushort* __restrict__ AXH, const ushort* __restrict__ AXL,
    const uint*  __restrict__ CTX,
    const ushort* __restrict__ BYH, const ushort* __restrict__ BYL,
    const uint*  __restrict__ CTY, float* __restrict__ out)
{
    const int t   = threadIdx.x;
    const int wv  = t >> 6, ln = t & 63;
    const int col = ln & 15, kb = ln >> 4;
    const int j0  = blockIdx.y * 64 + wv * 16;
    const int jt  = blockIdx.y * 4 + wv;          // j-tile index
    const int ib  = blockIdx.x * (NIT * 16);

    // resident B-side fragments: 16 contiguous 1KB wave-loads
    short8 Bh[8], Bl[8];
    uint   cvY[8];
    {
        const size_t bofs = ((size_t)jt * 8) * 512 + (size_t)col * 32 + kb * 8;
        const ushort* bh = BYH + bofs;
        const ushort* bl = BYL + bofs;
#pragma unroll
        for (int q = 0; q < 8; ++q) {
            Bh[q] = *reinterpret_cast<const short8*>(bh + q * 512);
            Bl[q] = *reinterpret_cast<const short8*>(bl + q * 512);
        }
        uint4 cy0 = make_uint4(0, 0, 0, 0), cy1 = make_uint4(0, 0, 0, 0);
        if (kb == 2) {
            cy0 = *reinterpret_cast<const uint4*>(CTY + (size_t)(j0 + col) * 8);
            cy1 = *reinterpret_cast<const uint4*>(CTY + (size_t)(j0 + col) * 8 + 4);
        }
        cvY[0] = cy0.x; cvY[1] = cy0.y; cvY[2] = cy0.z; cvY[3] = cy0.w;
        cvY[4] = cy1.x; cvY[5] = cy1.y; cvY[6] = cy1.z; cvY[7] = cy1.w;
    }
    const float P1 = 0.69314718055994530942f;   // ln2
    const float P2 = 0.16013630893549922444f;   // ln2^2/3

#pragma unroll
    for (int it = 0; it < NIT; ++it) {
        const int i0    = ib + it * 16;
        const int itile = (ib >> 4) + it;
        const size_t aofs = ((size_t)itile * 8) * 512 + (size_t)col * 32 + kb * 8;
        const ushort* ah = AXH + aofs;
        const ushort* al = AXL + aofs;

        uint cvX[8];
        {
            uint4 cx0 = make_uint4(0, 0, 0, 0), cx1 = make_uint4(0, 0, 0, 0);
            if (kb == 2) {
                cx0 = *reinterpret_cast<const uint4*>(CTX + (size_t)(i0 + col) * 8);
                cx1 = *reinterpret_cast<const uint4*>(CTX + (size_t)(i0 + col) * 8 + 4);
            }
            cvX[0] = cx0.x; cvX[1] = cx0.y; cvX[2] = cx0.z; cvX[3] = cx0.w;
            cvX[4] = cx1.x; cvX[5] = cx1.y; cvX[6] = cx1.z; cvX[7] = cx1.w;
        }

        f32x4 kacc = {0.f, 0.f, 0.f, 0.f};
#pragma unroll
        for (int q = 0; q < 8; ++q) {
            const short8 Ah = *reinterpret_cast<const short8*>(ah + q * 512);
            const short8 Al = *reinterpret_cast<const short8*>(al + q * 512);
            const f32x4 z = {0.f, 0.f, 0.f, 0.f};
            f32x4 au = __builtin_amdgcn_mfma_f32_16x16x32_bf16(Ah, Bh[q], z, 0, 0, 0);
            au = __builtin_amdgcn_mfma_f32_16x16x32_bf16(Al, Bh[q], au, 0, 0, 0);
            au = __builtin_amdgcn_mfma_f32_16x16x32_bf16(Ah, Bl[q], au, 0, 0, 0);
            const f32x4 ac = __builtin_amdgcn_mfma_f32_16x16x32_bf16(
                ct_frag(cvX[q]), ct_frag(cvY[q]), z, 0, 0, 0);
#pragma unroll
            for (int e = 0; e < 4; ++e) {
                const float u  = au[e];
                const float po = fmaf(u, fmaf(u, P2, P1), 1.0f);
                const float ex = __builtin_amdgcn_exp2f(-u);
                kacc[e] = fmaf(po * ex, ac[e], kacc[e]);
            }
        }
        // D layout: row = kb*4+e, col = lane&15  [m89-verified]
#pragma unroll
        for (int e = 0; e < 4; ++e)
            __builtin_nontemporal_store(
                kacc[e], out + (size_t)(i0 + kb * 4 + e) * NPTS + j0 + col);
    }
}

extern "C" void kernel_launch(void* const* d_in, const int* in_sizes, int n_in,
                              void* d_out, int out_size, void* d_ws, size_t ws_size,
                              hipStream_t stream) {
    const float* x  = (const float*)d_in[0];
    const float* y  = (const float*)d_in[1];
    const float* W1 = (const float*)d_in[2];
    const float* b1 = (const float*)d_in[3];
    const float* Ww = (const float*)d_in[4];
    const float* bw = (const float*)d_in[5];
    const float* Wf = (const float*)d_in[6];
    const float* bf = (const float*)d_in[7];
    const float* Ws = (const float*)d_in[8];
    const float* bs = (const float*)d_in[9];
    float* out = (float*)d_out;

    ushort* AXH = (ushort*)d_ws;                 // [128 tiles][8 q][16 col][4 kb][8]
    ushort* AXL = AXH + (size_t)NPTS * 256;      // lo
    ushort* BYH = AXL + (size_t)NPTS * 256;
    ushort* BYL = BYH + (size_t)NPTS * 256;
    uint*   CTX = (uint*)(BYL + (size_t)NPTS * 256);  // [2048][8] packed {wc,ws}
    uint*   CTY = CTX + (size_t)NPTS * 8;

    feat_kernel<<<dim3((2 * NPTS) / 8), dim3(640), 0, stream>>>(
        x, y, W1, b1, Ww, bw, Wf, bf, Ws, bs, AXH, AXL, BYH, BYL, CTX, CTY);

    // (64 i-strips of 32 rows, 32 j-blocks of 64 cols) = 2048 blocks
    pair_kernel<<<dim3(NPTS / (NIT * 16), NPTS / 64), dim3(256), 0, stream>>>(
        AXH, AXL, CTX, BYH, BYL, CTY, out);
}

// Round 14
// 47.989 us; speedup vs baseline: 1.2880x; 1.0250x over previous
//
#include <hip/hip_runtime.h>
#include <hip/hip_bf16.h>

#define NPTS 2048      // N == M == 2048
#define QMIX 8
#define LATD 64
#define NIT  8         // i-tiles (16 rows each) per pair block

typedef float f32x4 __attribute__((ext_vector_type(4)));
typedef short short8 __attribute__((ext_vector_type(8)));   // 8 bf16 (4 VGPRs)

__device__ __forceinline__ float softplus_f(float x) {
    return fmaxf(x, 0.0f) + log1pf(expf(-fabsf(x)));
}
__device__ __forceinline__ float selu_f(float z) {
    const float sc = 1.0507009873554805f;
    const float sa = 1.7580993408473766f;
    return (z > 0.0f) ? sc * z : sa * expm1f(z);
}
__device__ __forceinline__ ushort bfrn(float v) {   // round-to-nearest bf16
    unsigned b = __float_as_uint(v);
    return (ushort)((b + 0x7fffu + ((b >> 16) & 1u)) >> 16);
}
__device__ __forceinline__ void split_bf16(float v, ushort& h, ushort& l) {
    unsigned b  = __float_as_uint(v);
    unsigned hb = b & 0xffff0000u;          // truncated hi
    h = (ushort)(hb >> 16);
    l = bfrn(v - __uint_as_float(hb));      // rounded residual
}
__device__ __forceinline__ short8 ct_frag(uint av) {
    // nonzero bf16 pair at elements 4,5 (k-slots 20,21 for the kb==2 group)
    int4 r; r.x = 0; r.y = 0; r.z = (int)av; r.w = 0;
    return __builtin_bit_cast(short8, r);
}

// Slot layout per (point, q), 32 bf16 slots (hi + lo arrays):
//  X rows: [0..9]=coef, [10..19]=monomials, [20..31]=0
//  Y rows: [0..9]=monomials, [10..19]=coef, [20..31]=0
//  coef      = EF*[A00,A11,A22,2A01,2A02,2A12, -2Ax0,-2Ax1,-2Ax2, pAp]
//  monomials = [p0^2,p1^2,p2^2,p0p1,p0p2,p1p2, p0,p1,p2, 1]
//  => dot(Xrow[i,q], Yrow[j,q]) = EF*(qx+qy) = u;  exp(-sqrt5*r)=exp2(-u)
//
// FRAGMENT-READY TILED STORAGE: element (pt, q, k-chunk kb) lives at
//   ushort_ofs = ((pt>>4)*8 + q)*512 + (pt&15)*32 + kb*8
// so a wave (lane = (col, kb)) loading tile/q reads ONE contiguous 1KB block.
// CTX/CTY[pt*8+q] = packed bf16 {w*cos, w*sin}  (K=2 cosine dot, slots 20/21)
__global__ __launch_bounds__(640) void feat_kernel(
    const float* __restrict__ xin, const float* __restrict__ yin,
    const float* __restrict__ W1, const float* __restrict__ b1,
    const float* __restrict__ Ww, const float* __restrict__ bw,
    const float* __restrict__ Wf, const float* __restrict__ bf,
    const float* __restrict__ Ws, const float* __restrict__ bs,
    ushort* __restrict__ AXH, ushort* __restrict__ AXL,
    ushort* __restrict__ BYH, ushort* __restrict__ BYL,
    uint* __restrict__ CTX, uint* __restrict__ CTY)
{
    __shared__ float hsh[8][LATD + 4];
    __shared__ float raw[8][80];
    const int t = threadIdx.x;

    // phase 1: hidden layer
    if (t < 512) {
        const int pl = t & 7, l = t >> 3;
        const int g = blockIdx.x * 8 + pl;
        const bool isx = (g < NPTS);
        const float* pts = isx ? (xin + 3 * g) : (yin + 3 * (g - NPTS));
        const float z = fmaf(W1[l * 3 + 0], pts[0],
                        fmaf(W1[l * 3 + 1], pts[1],
                        fmaf(W1[l * 3 + 2], pts[2], b1[l])));
        hsh[pl][l] = selu_f(z);
    }
    __syncthreads();

    // phase 2: head dots
    {
        const int o  = t >> 3;
        const int pl = t & 7;
        const int q  = o / 10;
        const int e  = o % 10;
        const float* row;
        float acc;
        if (e == 0)      { row = Ww + q * LATD;                 acc = bw[q]; }
        else if (e <= 3) { row = Wf + (q * 3 + (e - 1)) * LATD; acc = bf[q * 3 + (e - 1)]; }
        else             { row = Ws + (q * 6 + (e - 4)) * LATD; acc = bs[q * 6 + (e - 4)]; }
#pragma unroll
        for (int l4 = 0; l4 < LATD / 4; ++l4) {
            const float4 rv = reinterpret_cast<const float4*>(row)[l4];
            const float4 hv = *reinterpret_cast<const float4*>(&hsh[pl][l4 * 4]);
            acc = fmaf(rv.x, hv.x, acc);
            acc = fmaf(rv.y, hv.y, acc);
            acc = fmaf(rv.z, hv.z, acc);
            acc = fmaf(rv.w, hv.w, acc);
        }
        raw[pl][o] = softplus_f(acc);
    }
    __syncthreads();

    // phase 3: expand quadratic form and emit split-bf16 rows (tiled layout)
    if (t < 64) {
        const int pl2 = t >> 3, q2 = t & 7;
        const int g2  = blockIdx.x * 8 + pl2;
        const bool isx2 = (g2 < NPTS);
        const float* pts2 = isx2 ? (xin + 3 * g2) : (yin + 3 * (g2 - NPTS));
        const float c0 = pts2[0], c1 = pts2[1], c2 = pts2[2];
        const float* rr = raw[pl2] + q2 * 10;
        const float w  = rr[0];
        const float f0 = rr[1], f1 = rr[2], f2 = rr[3];
        const float s0 = rr[4], s1 = rr[5], s2 = rr[6];
        const float s3 = rr[7], s4 = rr[8], s5 = rr[9];

        // A = L L^T
        const float A00 = s0 * s0;
        const float A01 = s0 * s1;
        const float A02 = s0 * s3;
        const float A11 = fmaf(s1, s1, s2 * s2);
        const float A12 = fmaf(s1, s3, s2 * s4);
        const float A22 = fmaf(s3, s3, fmaf(s4, s4, s5 * s5));
        const float Ax0 = fmaf(A00, c0, fmaf(A01, c1, A02 * c2));
        const float Ax1 = fmaf(A01, c0, fmaf(A11, c1, A12 * c2));
        const float Ax2 = fmaf(A02, c0, fmaf(A12, c1, A22 * c2));
        const float pAp = fmaf(c0, Ax0, fmaf(c1, Ax1, c2 * Ax2));
        const float ph  = fmaf(f0, c0, fmaf(f1, c1, f2 * c2));
        float sn, cs;
        sincosf(6.283185307179586477f * ph, &sn, &cs);

        const float EF = 3.2259751249059600974f;   // sqrt(5)*log2(e)
        const float cf[10] = { EF * A00, EF * A11, EF * A22,
                               2.0f * EF * A01, 2.0f * EF * A02, 2.0f * EF * A12,
                               -2.0f * EF * Ax0, -2.0f * EF * Ax1, -2.0f * EF * Ax2,
                               EF * pAp };
        const float pv[10] = { c0 * c0, c1 * c1, c2 * c2,
                               c0 * c1, c0 * c2, c1 * c2,
                               c0, c1, c2, 1.0f };
        float slots[20];
#pragma unroll
        for (int k = 0; k < 10; ++k) {
            slots[k]      = isx2 ? cf[k] : pv[k];
            slots[10 + k] = isx2 ? pv[k] : cf[k];
        }
        ushort H[32], L[32];
#pragma unroll
        for (int k = 0; k < 32; ++k) { H[k] = 0; L[k] = 0; }
#pragma unroll
        for (int k = 0; k < 20; ++k) split_bf16(slots[k], H[k], L[k]);

        const int pi = isx2 ? g2 : (g2 - NPTS);
        const size_t ofs = (((size_t)(pi >> 4) * 8 + q2) * 512) + (size_t)(pi & 15) * 32;
        ushort* dh = (isx2 ? AXH : BYH) + ofs;
        ushort* dl = (isx2 ? AXL : BYL) + ofs;
#pragma unroll
        for (int m = 0; m < 16; ++m) {
            ((uint*)dh)[m] = (uint)H[2 * m] | ((uint)H[2 * m + 1] << 16);
            ((uint*)dl)[m] = (uint)L[2 * m] | ((uint)L[2 * m + 1] << 16);
        }
        uint* ct = isx2 ? CTX : CTY;
        ct[(size_t)pi * 8 + q2] = (uint)bfrn(w * cs) | ((uint)bfrn(w * sn) << 16);
    }
}

// Pair kernel r14: no LDS, no barriers, deep per-wave i-loop (NIT=8) with
// REGISTER double-buffered A-tile prefetch: next tile's 16 loads issue
// before the current tile's MFMAs, so load latency hides under compute.
// MFMA chains broken to depth 2 (aa/ab parallel). 512 blocks = 2/CU, all
// resident, zero tail; B prologue amortized over 8 tiles.
__global__ __launch_bounds__(256) void pair_kernel(
    const ushort* __restrict__ AXH, const ushort* __restrict__ AXL,
    const uint*  __restrict__ CTX,
    const ushort* __restrict__ BYH, const ushort* __restrict__ BYL,
    const uint*  __restrict__ CTY, float* __restrict__ out)
{
    const int t   = threadIdx.x;
    const int wv  = t >> 6, ln = t & 63;
    const int col = ln & 15, kb = ln >> 4;
    const int j0  = blockIdx.y * 64 + wv * 16;
    const int jt  = blockIdx.y * 4 + wv;          // j-tile index
    const int itb = blockIdx.x * NIT;             // first i-tile of this block

    // resident B-side fragments: 16 contiguous 1KB wave-loads
    short8 Bh[8], Bl[8];
    uint   cvY[8];
    {
        const size_t bofs = ((size_t)jt * 8) * 512 + (size_t)col * 32 + kb * 8;
        const ushort* bh = BYH + bofs;
        const ushort* bl = BYL + bofs;
#pragma unroll
        for (int q = 0; q < 8; ++q) {
            Bh[q] = *reinterpret_cast<const short8*>(bh + q * 512);
            Bl[q] = *reinterpret_cast<const short8*>(bl + q * 512);
        }
        uint4 cy0 = make_uint4(0, 0, 0, 0), cy1 = make_uint4(0, 0, 0, 0);
        if (kb == 2) {
            cy0 = *reinterpret_cast<const uint4*>(CTY + (size_t)(j0 + col) * 8);
            cy1 = *reinterpret_cast<const uint4*>(CTY + (size_t)(j0 + col) * 8 + 4);
        }
        cvY[0] = cy0.x; cvY[1] = cy0.y; cvY[2] = cy0.z; cvY[3] = cy0.w;
        cvY[4] = cy1.x; cvY[5] = cy1.y; cvY[6] = cy1.z; cvY[7] = cy1.w;
    }
    const float P1 = 0.69314718055994530942f;   // ln2
    const float P2 = 0.16013630893549922444f;   // ln2^2/3

    short8 curH[8], curL[8], nxtH[8], nxtL[8];

#define LOADA(TILE, H, L)                                                     \
    {                                                                         \
        const size_t aofs_ = ((size_t)(TILE) * 8) * 512                       \
                           + (size_t)col * 32 + kb * 8;                       \
        const ushort* ah_ = AXH + aofs_;                                      \
        const ushort* al_ = AXL + aofs_;                                      \
        _Pragma("unroll")                                                     \
        for (int q = 0; q < 8; ++q) {                                         \
            H[q] = *reinterpret_cast<const short8*>(ah_ + q * 512);           \
            L[q] = *reinterpret_cast<const short8*>(al_ + q * 512);           \
        }                                                                     \
    }

#define COMPUTE(ITILE, H, L)                                                  \
    {                                                                         \
        const int i0_ = (ITILE) * 16;                                         \
        uint cvX[8];                                                          \
        {                                                                     \
            uint4 cx0 = make_uint4(0, 0, 0, 0), cx1 = make_uint4(0, 0, 0, 0); \
            if (kb == 2) {                                                    \
                cx0 = *reinterpret_cast<const uint4*>(                        \
                    CTX + (size_t)(i0_ + col) * 8);                           \
                cx1 = *reinterpret_cast<const uint4*>(                        \
                    CTX + (size_t)(i0_ + col) * 8 + 4);                       \
            }                                                                 \
            cvX[0] = cx0.x; cvX[1] = cx0.y; cvX[2] = cx0.z; cvX[3] = cx0.w;   \
            cvX[4] = cx1.x; cvX[5] = cx1.y; cvX[6] = cx1.z; cvX[7] = cx1.w;   \
        }                                                                     \
        f32x4 kacc = {0.f, 0.f, 0.f, 0.f};                                    \
        _Pragma("unroll")                                                     \
        for (int q = 0; q < 8; ++q) {                                         \
            const f32x4 z = {0.f, 0.f, 0.f, 0.f};                            \
            f32x4 aa = __builtin_amdgcn_mfma_f32_16x16x32_bf16(               \
                H[q], Bh[q], z, 0, 0, 0);                                     \
            f32x4 ab = __builtin_amdgcn_mfma_f32_16x16x32_bf16(               \
                L[q], Bh[q], z, 0, 0, 0);                                     \
            aa = __builtin_amdgcn_mfma_f32_16x16x32_bf16(                     \
                H[q], Bl[q], aa, 0, 0, 0);                                    \
            const f32x4 ac = __builtin_amdgcn_mfma_f32_16x16x32_bf16(         \
                ct_frag(cvX[q]), ct_frag(cvY[q]), z, 0, 0, 0);                \
            _Pragma("unroll")                                                 \
            for (int e = 0; e < 4; ++e) {                                     \
                const float u_  = aa[e] + ab[e];                              \
                const float po_ = fmaf(u_, fmaf(u_, P2, P1), 1.0f);           \
                const float ex_ = __builtin_amdgcn_exp2f(-u_);                \
                kacc[e] = fmaf(po_ * ex_, ac[e], kacc[e]);                    \
            }                                                                 \
        }                                                                     \
        _Pragma("unroll")                                                     \
        for (int e = 0; e < 4; ++e)                                           \
            out[(size_t)(i0_ + kb * 4 + e) * NPTS + j0 + col] = kacc[e];      \
    }

    LOADA(itb, curH, curL)
#pragma unroll
    for (int it = 0; it < NIT; it += 2) {
        const int pf1 = min(itb + it + 1, NPTS / 16 - 1);
        LOADA(pf1, nxtH, nxtL)
        COMPUTE(itb + it, curH, curL)
        const int pf2 = min(itb + it + 2, NPTS / 16 - 1);
        LOADA(pf2, curH, curL)
        COMPUTE(itb + it + 1, nxtH, nxtL)
    }
#undef LOADA
#undef COMPUTE
}

extern "C" void kernel_launch(void* const* d_in, const int* in_sizes, int n_in,
                              void* d_out, int out_size, void* d_ws, size_t ws_size,
                              hipStream_t stream) {
    const float* x  = (const float*)d_in[0];
    const float* y  = (const float*)d_in[1];
    const float* W1 = (const float*)d_in[2];
    const float* b1 = (const float*)d_in[3];
    const float* Ww = (const float*)d_in[4];
    const float* bw = (const float*)d_in[5];
    const float* Wf = (const float*)d_in[6];
    const float* bf = (const float*)d_in[7];
    const float* Ws = (const float*)d_in[8];
    const float* bs = (const float*)d_in[9];
    float* out = (float*)d_out;

    ushort* AXH = (ushort*)d_ws;                 // [128 tiles][8 q][16 col][4 kb][8]
    ushort* AXL = AXH + (size_t)NPTS * 256;      // lo
    ushort* BYH = AXL + (size_t)NPTS * 256;
    ushort* BYL = BYH + (size_t)NPTS * 256;
    uint*   CTX = (uint*)(BYL + (size_t)NPTS * 256);  // [2048][8] packed {wc,ws}
    uint*   CTY = CTX + (size_t)NPTS * 8;

    feat_kernel<<<dim3((2 * NPTS) / 8), dim3(640), 0, stream>>>(
        x, y, W1, b1, Ww, bw, Wf, bf, Ws, bs, AXH, AXL, BYH, BYL, CTX, CTY);

    // (16 i-strips of 128 rows, 32 j-blocks of 64 cols) = 512 blocks, 2/CU
    pair_kernel<<<dim3(NPTS / (NIT * 16), NPTS / 64), dim3(256), 0, stream>>>(
        AXH, AXL, CTX, BYH, BYL, CTY, out);
}